// Round 6
// baseline (72008.752 us; speedup 1.0000x reference)
//
#include <hip/hip_runtime.h>
#include <hip/hip_bf16.h>

#define SEQ_LEN 256
#define NB 64
#define NV 10000
#define ND 1024
#define NBLK 256

typedef unsigned int u32;

__device__ __forceinline__ float sigf(float z) { return 1.f / (1.f + expf(-z)); }

__device__ __forceinline__ float dot8_f32(const float* hv, const float* wp, float acc) {
  float4 w0 = *(const float4*)wp;
  float4 w1 = *(const float4*)(wp + 4);
  acc += hv[0] * w0.x; acc += hv[1] * w0.y; acc += hv[2] * w0.z; acc += hv[3] * w0.w;
  acc += hv[4] * w1.x; acc += hv[5] * w1.y; acc += hv[6] * w1.z; acc += hv[7] * w1.w;
  return acc;
}

// ---- diagnostic flood (f32 out) ----
__global__ void floodk(float* out, float val, unsigned long long n) {
  unsigned long long i = (unsigned long long)blockIdx.x * 256 + threadIdx.x;
  if (i < n) out[i] = val;
}

// ---- init: transpose states to feature-major, zero barrier counter ----
__global__ void init_state(const float* __restrict__ h0, const float* __restrict__ c0,
                           float* __restrict__ hT, float* __restrict__ cT, u32* bar) {
  int i = blockIdx.x * 256 + threadIdx.x;   // 0..65535
  int k = i >> 6, b = i & 63;
  hT[i] = h0[b * ND + k];
  cT[i] = c0[b * ND + k];
  if (i == 0) *bar = 0u;
}

// ================= persistent fused sequence kernel =================
// grid 256 blocks x 512 thr (8 waves). 1 block/CU guaranteed co-resident.

__device__ __forceinline__ void gbar(u32* bar, u32& target) {
  __syncthreads();
  if (threadIdx.x == 0) {
    target += NBLK;
    __threadfence();
    __hip_atomic_fetch_add(bar, 1u, __ATOMIC_RELEASE, __HIP_MEMORY_SCOPE_AGENT);
    while (__hip_atomic_load(bar, __ATOMIC_ACQUIRE, __HIP_MEMORY_SCOPE_AGENT) < target) {
      __builtin_amdgcn_s_sleep(2);
    }
    __threadfence();
  }
  __syncthreads();
}

// mog phase: out[c][b] = 2*sig(sum_k act[k][b]*W[c][k] + bias[c]) * mult
// block owns 4 cols; 8 waves split K into 128-chunks; LDS reduce.
template<bool EMB>
__device__ __forceinline__ void mogP(
    const float* __restrict__ actT, const float* __restrict__ W,
    const float* __restrict__ bias, const float* __restrict__ emb,
    const int* __restrict__ tok, const float* __restrict__ multT,
    float* __restrict__ outT, float* red)
{
  const int tid = threadIdx.x;
  const int wv = tid >> 6, lane = tid & 63;
  const int c0 = blockIdx.x * 4;
  const int kb = wv * 128;
  float acc[4] = {0.f, 0.f, 0.f, 0.f};
  const float* ap = actT + (size_t)kb * NB + lane;

  for (int k = 0; k < 128; k += 8) {
    float hv[8];
#pragma unroll
    for (int q = 0; q < 8; ++q) hv[q] = ap[(k + q) * NB];
#pragma unroll
    for (int c = 0; c < 4; ++c)
      acc[c] = dot8_f32(hv, W + (size_t)(c0 + c) * ND + kb + k, acc[c]);
  }
#pragma unroll
  for (int c = 0; c < 4; ++c) red[(wv * 16 + c) * 64 + lane] = acc[c];
  __syncthreads();

  if (tid < 256) {
    const int c = tid >> 6, b = tid & 63;
    float z = 0.f;
#pragma unroll
    for (int w = 0; w < 8; ++w) z += red[(w * 16 + c) * 64 + b];
    z += bias[c0 + c];
    float g = 2.f * sigf(z);
    float m = EMB ? emb[(size_t)tok[b] * ND + (c0 + c)]
                  : multT[(size_t)(c0 + c) * NB + b];
    outT[(size_t)(c0 + c) * NB + b] = g * m;
  }
}

// gates phase: block owns 4 hidden cols (16 gate rows); waves 0-3 = x-half,
// 4-7 = h-half, each a K-chunk of 256; LDS reduce + state update.
__device__ __forceinline__ void gatesP(
    const float* __restrict__ xT, const float* __restrict__ hT,
    const float* __restrict__ Wih, const float* __restrict__ Whh,
    const float* __restrict__ bih, const float* __restrict__ bhh,
    float* __restrict__ cT, float* __restrict__ hOut, float* red)
{
  const int tid = threadIdx.x;
  const int wv = tid >> 6, lane = tid & 63;
  const int j0 = blockIdx.x * 4;
  const int half = wv >> 2, kq = wv & 3;
  const int kb = kq * 256;
  const float* ap = (half ? hT : xT) + (size_t)kb * NB + lane;
  const float* Wb = half ? Whh : Wih;

  float acc[16];
#pragma unroll
  for (int i = 0; i < 16; ++i) acc[i] = 0.f;

  for (int k = 0; k < 256; k += 8) {
    float av[8];
#pragma unroll
    for (int q = 0; q < 8; ++q) av[q] = ap[(k + q) * NB];
#pragma unroll
    for (int jj = 0; jj < 4; ++jj)
#pragma unroll
      for (int g = 0; g < 4; ++g) {
        const size_t row = (size_t)(g * ND + j0 + jj) * ND + kb + k;
        acc[jj * 4 + g] = dot8_f32(av, Wb + row, acc[jj * 4 + g]);
      }
  }
#pragma unroll
  for (int i = 0; i < 16; ++i) red[(wv * 16 + i) * 64 + lane] = acc[i];
  __syncthreads();

  if (tid < 256) {
    const int jj = tid >> 6, b = tid & 63;
    const int j = j0 + jj;
    float pre[4];
#pragma unroll
    for (int g = 0; g < 4; ++g) {
      float s = 0.f;
#pragma unroll
      for (int w = 0; w < 8; ++w) s += red[(w * 16 + jj * 4 + g) * 64 + b];
      pre[g] = s + bih[g * ND + j] + bhh[g * ND + j];
    }
    float iv = sigf(pre[0]), fv = sigf(pre[1]);
    float gv = tanhf(pre[2]), ov = sigf(pre[3]);
    float cn = fv * cT[(size_t)j * NB + b] + iv * gv;
    float hn = ov * tanhf(cn);
    cT[(size_t)j * NB + b] = cn;
    hOut[(size_t)j * NB + b] = hn;
  }
}

__global__ __launch_bounds__(512) void seq_kernel(
    const int* __restrict__ tokens, const float* __restrict__ emb,
    const float* __restrict__ qw, const float* __restrict__ qb,
    const float* __restrict__ rw, const float* __restrict__ rb,
    const float* __restrict__ wih, const float* __restrict__ whh,
    const float* __restrict__ bih, const float* __restrict__ bhh,
    float* __restrict__ xA, float* __restrict__ xB,
    float* __restrict__ h1, float* __restrict__ h3,
    float* __restrict__ cS, float* __restrict__ hHist, u32* bar)
{
  __shared__ float red[8 * 16 * 64];
  u32 target = 0;
  const size_t DH = (size_t)ND * ND;
  const size_t SB = (size_t)ND * NB;

  for (int t = 0; t < SEQ_LEN; ++t) {
    const int* tok = tokens + (size_t)t * NB;
    float* hc = hHist + (size_t)t * SB;
    float* hn = hc + SB;
    mogP<true >(hc, qw, qb, emb, tok, nullptr, xA, red);        gbar(bar, target);
    mogP<false>(xA, rw, rb, nullptr, nullptr, hc, h1, red);     gbar(bar, target);
    mogP<false>(h1, qw + DH, qb + ND, nullptr, nullptr, xA, xB, red); gbar(bar, target);
    mogP<false>(xB, rw + DH, rb + ND, nullptr, nullptr, h1, h3, red); gbar(bar, target);
    gatesP(xB, h3, wih, whh, bih, bhh, cS, hn, red);            gbar(bar, target);
  }
}

// ================= fallback multi-launch kernels (proven) =================

template<bool EMB>
__global__ __launch_bounds__(256) void mog_phase(
    const float* __restrict__ actT, const float* __restrict__ W,
    const float* __restrict__ bias, const float* __restrict__ multT,
    const float* __restrict__ emb, const int* __restrict__ tok,
    float* __restrict__ outT)
{
  const int tid = threadIdx.x;
  const int wv = tid >> 6;
  const int lane = tid & 63;
  const int c0 = blockIdx.x * 4;
  __shared__ float red[4][4][64];

  float acc[4] = {0.f, 0.f, 0.f, 0.f};
  const int kb = wv * 256;
  const float* ap = actT + (size_t)kb * NB + lane;

  for (int k = 0; k < 256; k += 8) {
    float hv[8];
#pragma unroll
    for (int q = 0; q < 8; ++q) hv[q] = ap[(k + q) * NB];
#pragma unroll
    for (int c = 0; c < 4; ++c)
      acc[c] = dot8_f32(hv, W + (size_t)(c0 + c) * ND + kb + k, acc[c]);
  }
#pragma unroll
  for (int c = 0; c < 4; ++c) red[wv][c][lane] = acc[c];
  __syncthreads();

  const int c = tid >> 6, b = tid & 63;
  float z = red[0][c][b] + red[1][c][b] + red[2][c][b] + red[3][c][b];
  z += bias[c0 + c];
  float g = 2.f * sigf(z);
  float m;
  if (EMB) m = emb[(size_t)tok[b] * ND + (c0 + c)];
  else     m = multT[(size_t)(c0 + c) * NB + b];
  outT[(size_t)(c0 + c) * NB + b] = g * m;
}

__global__ __launch_bounds__(256) void lstm_gates2(
    const float* __restrict__ xT, const float* __restrict__ hT,
    const float* __restrict__ Wih, const float* __restrict__ Whh,
    const float* __restrict__ bih, const float* __restrict__ bhh,
    float* __restrict__ cT, float* __restrict__ hOut)
{
  const int tid = threadIdx.x;
  const int wv = tid >> 6, lane = tid & 63;
  const int j0 = blockIdx.x * 2;
  __shared__ float red[4][16][64];
  float acc[16];
#pragma unroll
  for (int i = 0; i < 16; ++i) acc[i] = 0.f;
  const int kb = wv * 256;
  const float* xp = xT + (size_t)kb * NB + lane;
  const float* hp = hT + (size_t)kb * NB + lane;

  for (int k = 0; k < 256; k += 8) {
    float xv[8], hv[8];
#pragma unroll
    for (int q = 0; q < 8; ++q) { xv[q] = xp[(k + q) * NB]; hv[q] = hp[(k + q) * NB]; }
#pragma unroll
    for (int jj = 0; jj < 2; ++jj)
#pragma unroll
      for (int g = 0; g < 4; ++g) {
        const size_t row = (size_t)(g * ND + j0 + jj) * ND + kb + k;
        acc[jj * 8 + g]     = dot8_f32(xv, Wih + row, acc[jj * 8 + g]);
        acc[jj * 8 + 4 + g] = dot8_f32(hv, Whh + row, acc[jj * 8 + 4 + g]);
      }
  }
#pragma unroll
  for (int i = 0; i < 16; ++i) red[wv][i][lane] = acc[i];
  __syncthreads();

  if (tid < 128) {
    const int b = tid & 63, jj = tid >> 6;
    const int j = j0 + jj;
    float pre[4];
#pragma unroll
    for (int g = 0; g < 4; ++g) {
      float s = 0.f;
#pragma unroll
      for (int w = 0; w < 4; ++w) s += red[w][jj * 8 + g][b] + red[w][jj * 8 + 4 + g][b];
      pre[g] = s + bih[g * ND + j] + bhh[g * ND + j];
    }
    float iv = sigf(pre[0]), fv = sigf(pre[1]);
    float gv = tanhf(pre[2]), ov = sigf(pre[3]);
    float cn = fv * cT[(size_t)j * NB + b] + iv * gv;
    float hn = ov * tanhf(cn);
    cT[(size_t)j * NB + b] = cn;
    hOut[(size_t)j * NB + b] = hn;
  }
}

__global__ __launch_bounds__(256) void decode_k(
    const float* __restrict__ hT, const float* __restrict__ W,
    const float* __restrict__ decb, float* __restrict__ out)
{
  const int tid = threadIdx.x;
  const int wv = tid >> 6, lane = tid & 63;
  const int v0 = blockIdx.x * 4;
  __shared__ float red[4][4][64];
  float acc[4] = {0.f, 0.f, 0.f, 0.f};
  const int kb = wv * 256;
  const float* hp = hT + (size_t)kb * NB + lane;

  for (int k = 0; k < 256; k += 8) {
    float hv[8];
#pragma unroll
    for (int q = 0; q < 8; ++q) hv[q] = hp[(k + q) * NB];
#pragma unroll
    for (int c = 0; c < 4; ++c)
      acc[c] = dot8_f32(hv, W + (size_t)(v0 + c) * ND + kb + k, acc[c]);
  }
#pragma unroll
  for (int c = 0; c < 4; ++c) red[wv][c][lane] = acc[c];
  __syncthreads();

  const int c = tid >> 6, b = tid & 63;
  float z = red[0][c][b] + red[1][c][b] + red[2][c][b] + red[3][c][b];
  z += decb[v0 + c];
  out[(size_t)b * NV + v0 + c] = z;
}

// ---- batched decode GEMM over the whole h-history ----
__global__ __launch_bounds__(256) void decode_gemm(
    const float* __restrict__ A,      // [t][k][b]
    const float* __restrict__ Bw,     // [n][k]
    const float* __restrict__ bias,
    float* __restrict__ C)            // [t][b][n]
{
  const int tid = threadIdx.x;
  const int bid = blockIdx.x;
  const int mt = bid & 255;
  const int nt = bid >> 8;
  const int n0 = nt * 64;

  __shared__ float As[2048];
  __shared__ float Bs[2048];

  const int tm = tid >> 4, tn = tid & 15;
  float acc[4][4] = {{0.f}};
  const float* Abase = A + (size_t)mt * (ND * NB);

  for (int k0 = 0; k0 < ND; k0 += 32) {
    __syncthreads();
    {
      const float4* src = (const float4*)(Abase + (size_t)k0 * NB);
      ((float4*)As)[tid] = src[tid];
      ((float4*)As)[tid + 256] = src[tid + 256];
    }
#pragma unroll
    for (int i = 0; i < 2; ++i) {
      int f = tid + i * 256;
      int n = f >> 3;
      int kc = f & 7;
      int gn = n0 + n;
      float4 v = make_float4(0.f, 0.f, 0.f, 0.f);
      if (gn < NV) v = *(const float4*)(Bw + (size_t)gn * ND + k0 + kc * 4);
      int k = kc * 4;
      int n4 = n >> 2, nr = n & 3;
      Bs[(k + 0) * 64 + ((n4 ^ ((k + 0) & 7)) << 2) + nr] = v.x;
      Bs[(k + 1) * 64 + ((n4 ^ ((k + 1) & 7)) << 2) + nr] = v.y;
      Bs[(k + 2) * 64 + ((n4 ^ ((k + 2) & 7)) << 2) + nr] = v.z;
      Bs[(k + 3) * 64 + ((n4 ^ ((k + 3) & 7)) << 2) + nr] = v.w;
    }
    __syncthreads();
#pragma unroll
    for (int kk = 0; kk < 32; ++kk) {
      float a4[4], b4[4];
      *(float4*)a4 = *(const float4*)(As + kk * 64 + tm * 4);
      *(float4*)b4 = *(const float4*)(Bs + kk * 64 + ((tn ^ (kk & 7)) << 2));
#pragma unroll
      for (int i = 0; i < 4; ++i)
#pragma unroll
        for (int j = 0; j < 4; ++j)
          acc[i][j] = fmaf(a4[i], b4[j], acc[i][j]);
    }
  }

  const int nb = n0 + tn * 4;
  float db[4];
#pragma unroll
  for (int j = 0; j < 4; ++j) db[j] = (nb + j < NV) ? bias[nb + j] : 0.f;
  float* Crow = C + (size_t)mt * ((size_t)NB * NV);
#pragma unroll
  for (int i = 0; i < 4; ++i) {
    const int b = tm * 4 + i;
    float* cp = Crow + (size_t)b * NV + nb;
    if (nb + 3 < NV) {
      float4 v;
      v.x = acc[i][0] + db[0]; v.y = acc[i][1] + db[1];
      v.z = acc[i][2] + db[2]; v.w = acc[i][3] + db[3];
      *(float4*)cp = v;
    } else {
#pragma unroll
      for (int j = 0; j < 4; ++j)
        if (nb + j < NV) cp[j] = acc[i][j] + db[j];
    }
  }
}

__global__ void finalize(const float* __restrict__ hT, const float* __restrict__ cT,
                         float* __restrict__ out) {
  int i = blockIdx.x * 256 + threadIdx.x;
  int k = i >> 6, b = i & 63;
  size_t base = (size_t)SEQ_LEN * NB * NV;
  out[base + (size_t)b * ND + k] = hT[i];
  out[base + (size_t)NB * ND + (size_t)b * ND + k] = cT[i];
}

extern "C" void kernel_launch(void* const* d_in, const int* in_sizes, int n_in,
                              void* d_out, int out_size, void* d_ws, size_t ws_size,
                              hipStream_t stream)
{
  float* out = (float*)d_out;
  const unsigned long long expect_out = (unsigned long long)SEQ_LEN * NB * NV + 2ull * NB * ND;

  auto flood = [&](float v) {
    unsigned long long n = (unsigned long long)out_size;
    unsigned int g = (unsigned int)((n + 255) / 256);
    floodk<<<g, 256, 0, stream>>>(out, v, n);
  };
  const int expect_sz[14] = {
    SEQ_LEN * NB, NV * ND, 2 * ND * ND, 2 * ND, 2 * ND * ND, 2 * ND,
    4 * ND * ND, 4 * ND * ND, 4 * ND, 4 * ND, NV * ND, NV, NB * ND, NB * ND };
  if (n_in != 14) { flood(1000.f); return; }
  for (int i = 0; i < 14; ++i)
    if (in_sizes[i] != expect_sz[i]) { flood(1100.f + 100.f * i); return; }
  if ((unsigned long long)out_size != expect_out) { flood(2500.f); return; }

  float* ws = (float*)d_ws;
  const size_t SB = (size_t)ND * NB;   // 65536
  if (ws_size < 7 * SB * sizeof(float)) { flood(2600.f); return; }

  const int*   tokens = (const int*)d_in[0];
  const float* emb  = (const float*)d_in[1];
  const float* qw   = (const float*)d_in[2];
  const float* qb   = (const float*)d_in[3];
  const float* rw   = (const float*)d_in[4];
  const float* rb   = (const float*)d_in[5];
  const float* wih  = (const float*)d_in[6];
  const float* whh  = (const float*)d_in[7];
  const float* bih  = (const float*)d_in[8];
  const float* bhh  = (const float*)d_in[9];
  const float* decw = (const float*)d_in[10];
  const float* decb = (const float*)d_in[11];
  const float* h0   = (const float*)d_in[12];
  const float* c0   = (const float*)d_in[13];

  float* xA = ws + 0 * SB;
  float* xB = ws + 1 * SB;
  float* h1 = ws + 2 * SB;
  float* h3 = ws + 3 * SB;
  float* cS = ws + 4 * SB;
  float* hHist = ws + 5 * SB;          // 257 slots
  u32* bar = (u32*)(ws + (5 + SEQ_LEN + 1) * SB);

  const size_t DH = (size_t)ND * ND;
  const bool big = ws_size >= ((5 + SEQ_LEN + 1) * SB + 16) * sizeof(float);

  if (big) {
    init_state<<<256, 256, 0, stream>>>(h0, c0, hHist, cS, bar);
    seq_kernel<<<NBLK, 512, 0, stream>>>(tokens, emb, qw, qb, rw, rb,
                                         wih, whh, bih, bhh,
                                         xA, xB, h1, h3, cS, hHist, bar);
    decode_gemm<<<157 * 256, 256, 0, stream>>>(hHist + SB, decw, decb, out);
    finalize<<<256, 256, 0, stream>>>(hHist + (size_t)SEQ_LEN * SB, cS, out);
  } else {
    float* hA = hHist;
    float* hB = hHist + SB;
    init_state<<<256, 256, 0, stream>>>(h0, c0, hA, cS, bar);
    float* hc = hA;
    float* hn = hB;
    for (int t = 0; t < SEQ_LEN; ++t) {
      const int* tk = tokens + (size_t)t * NB;
      mog_phase<true ><<<256, 256, 0, stream>>>(hc, qw, qb, nullptr, emb, tk, xA);
      mog_phase<false><<<256, 256, 0, stream>>>(xA, rw, rb, hc, nullptr, nullptr, h1);
      mog_phase<false><<<256, 256, 0, stream>>>(h1, qw + DH, qb + ND, xA, nullptr, nullptr, xB);
      mog_phase<false><<<256, 256, 0, stream>>>(xB, rw + DH, rb + ND, h1, nullptr, nullptr, h3);
      lstm_gates2<<<512, 256, 0, stream>>>(xB, h3, wih, whh, bih, bhh, cS, hn);
      decode_k<<<2500, 256, 0, stream>>>(hn, decw, decb, out + (size_t)t * NB * NV);
      float* tmp = hc; hc = hn; hn = tmp;
    }
    finalize<<<256, 256, 0, stream>>>(hc, cS, out);
  }
}

// Round 7
// 65990.723 us; speedup vs baseline: 1.0912x; 1.0912x over previous
//
#include <hip/hip_runtime.h>
#include <hip/hip_bf16.h>

#define SEQ_LEN 256
#define NB 64
#define NV 10000
#define ND 1024
#define NBLK 256

typedef unsigned int u32;

__device__ __forceinline__ float sigf(float z) { return 1.f / (1.f + expf(-z)); }

__device__ __forceinline__ float dot8_f32(const float* hv, const float* wp, float acc) {
  float4 w0 = *(const float4*)wp;
  float4 w1 = *(const float4*)(wp + 4);
  acc += hv[0] * w0.x; acc += hv[1] * w0.y; acc += hv[2] * w0.z; acc += hv[3] * w0.w;
  acc += hv[4] * w1.x; acc += hv[5] * w1.y; acc += hv[6] * w1.z; acc += hv[7] * w1.w;
  return acc;
}

// ---- diagnostic flood (f32 out) ----
__global__ void floodk(float* out, float val, unsigned long long n) {
  unsigned long long i = (unsigned long long)blockIdx.x * 256 + threadIdx.x;
  if (i < n) out[i] = val;
}

// ---- init: transpose states to feature-major, zero barrier lines ----
__global__ void init_state(const float* __restrict__ h0, const float* __restrict__ c0,
                           float* __restrict__ hT, float* __restrict__ cT, u32* bar) {
  int i = blockIdx.x * 256 + threadIdx.x;   // 0..65535
  int k = i >> 6, b = i & 63;
  hT[i] = h0[b * ND + k];
  cT[i] = c0[b * ND + k];
  if (i < 64) bar[i] = 0u;                  // count @ bar[0], gen @ bar[32]
}

// ================= persistent fused sequence kernel =================
// grid 256 blocks x 512 thr (8 waves), 1 block/CU co-resident.
// Two-line barrier: arrival counter and generation flag on separate
// cachelines; only the LAST arriver publishes gen; spinners read-share gen.

__device__ __forceinline__ void gbar(u32* bar, u32& target) {
  __syncthreads();
  if (threadIdx.x == 0) {
    u32* cnt = bar;
    u32* gen = bar + 32;                    // 128 B away
    target += NBLK;
    __threadfence();
    u32 old = __hip_atomic_fetch_add(cnt, 1u, __ATOMIC_ACQ_REL, __HIP_MEMORY_SCOPE_AGENT);
    if (old == target - 1) {
      __hip_atomic_store(gen, target, __ATOMIC_RELEASE, __HIP_MEMORY_SCOPE_AGENT);
    } else {
      while (__hip_atomic_load(gen, __ATOMIC_ACQUIRE, __HIP_MEMORY_SCOPE_AGENT) < target) {
        __builtin_amdgcn_s_sleep(4);
      }
    }
    __threadfence();
  }
  __syncthreads();
}

// mog phase: out[c][b] = 2*sig(sum_k act[k][b]*W[c][k] + bias[c]) * mult
template<bool EMB>
__device__ __forceinline__ void mogP(
    const float* __restrict__ actT, const float* __restrict__ W,
    const float* __restrict__ bias, const float* __restrict__ emb,
    const int* __restrict__ tok, const float* __restrict__ multT,
    float* __restrict__ outT, float* red)
{
  const int tid = threadIdx.x;
  const int wv = tid >> 6, lane = tid & 63;
  const int c0 = blockIdx.x * 4;
  const int kb = wv * 128;
  float acc[4] = {0.f, 0.f, 0.f, 0.f};
  const float* ap = actT + (size_t)kb * NB + lane;

  for (int k = 0; k < 128; k += 8) {
    float hv[8];
#pragma unroll
    for (int q = 0; q < 8; ++q) hv[q] = ap[(k + q) * NB];
#pragma unroll
    for (int c = 0; c < 4; ++c)
      acc[c] = dot8_f32(hv, W + (size_t)(c0 + c) * ND + kb + k, acc[c]);
  }
#pragma unroll
  for (int c = 0; c < 4; ++c) red[(wv * 16 + c) * 64 + lane] = acc[c];
  __syncthreads();

  if (tid < 256) {
    const int c = tid >> 6, b = tid & 63;
    float z = 0.f;
#pragma unroll
    for (int w = 0; w < 8; ++w) z += red[(w * 16 + c) * 64 + b];
    z += bias[c0 + c];
    float g = 2.f * sigf(z);
    float m = EMB ? emb[(size_t)tok[b] * ND + (c0 + c)]
                  : multT[(size_t)(c0 + c) * NB + b];
    outT[(size_t)(c0 + c) * NB + b] = g * m;
  }
}

// gates phase: block owns 4 hidden cols (16 gate rows); waves 0-3 x-half,
// 4-7 h-half; LDS reduce + state update.
__device__ __forceinline__ void gatesP(
    const float* __restrict__ xT, const float* __restrict__ hT,
    const float* __restrict__ Wih, const float* __restrict__ Whh,
    const float* __restrict__ bih, const float* __restrict__ bhh,
    float* __restrict__ cT, float* __restrict__ hOut, float* red)
{
  const int tid = threadIdx.x;
  const int wv = tid >> 6, lane = tid & 63;
  const int j0 = blockIdx.x * 4;
  const int half = wv >> 2, kq = wv & 3;
  const int kb = kq * 256;
  const float* ap = (half ? hT : xT) + (size_t)kb * NB + lane;
  const float* Wb = half ? Whh : Wih;

  float acc[16];
#pragma unroll
  for (int i = 0; i < 16; ++i) acc[i] = 0.f;

  for (int k = 0; k < 256; k += 8) {
    float av[8];
#pragma unroll
    for (int q = 0; q < 8; ++q) av[q] = ap[(k + q) * NB];
#pragma unroll
    for (int jj = 0; jj < 4; ++jj)
#pragma unroll
      for (int g = 0; g < 4; ++g) {
        const size_t row = (size_t)(g * ND + j0 + jj) * ND + kb + k;
        acc[jj * 4 + g] = dot8_f32(av, Wb + row, acc[jj * 4 + g]);
      }
  }
#pragma unroll
  for (int i = 0; i < 16; ++i) red[(wv * 16 + i) * 64 + lane] = acc[i];
  __syncthreads();

  if (tid < 256) {
    const int jj = tid >> 6, b = tid & 63;
    const int j = j0 + jj;
    float pre[4];
#pragma unroll
    for (int g = 0; g < 4; ++g) {
      float s = 0.f;
#pragma unroll
      for (int w = 0; w < 8; ++w) s += red[(w * 16 + jj * 4 + g) * 64 + b];
      pre[g] = s + bih[g * ND + j] + bhh[g * ND + j];
    }
    float iv = sigf(pre[0]), fv = sigf(pre[1]);
    float gv = tanhf(pre[2]), ov = sigf(pre[3]);
    float cn = fv * cT[(size_t)j * NB + b] + iv * gv;
    float hn = ov * tanhf(cn);
    cT[(size_t)j * NB + b] = cn;
    hOut[(size_t)j * NB + b] = hn;
  }
}

__global__ __launch_bounds__(512) void seq_kernel(
    const int* __restrict__ tokens, const float* __restrict__ emb,
    const float* __restrict__ qw, const float* __restrict__ qb,
    const float* __restrict__ rw, const float* __restrict__ rb,
    const float* __restrict__ wih, const float* __restrict__ whh,
    const float* __restrict__ bih, const float* __restrict__ bhh,
    float* __restrict__ xA, float* __restrict__ xB,
    float* __restrict__ h1, float* __restrict__ h3,
    float* __restrict__ cS, float* __restrict__ hHist, u32* bar)
{
  __shared__ float red[8 * 16 * 64];
  u32 target = 0;
  const size_t DH = (size_t)ND * ND;
  const size_t SB = (size_t)ND * NB;

  for (int t = 0; t < SEQ_LEN; ++t) {
    const int* tok = tokens + (size_t)t * NB;
    float* hc = hHist + (size_t)t * SB;
    float* hn = hc + SB;
    mogP<true >(hc, qw, qb, emb, tok, nullptr, xA, red);        gbar(bar, target);
    mogP<false>(xA, rw, rb, nullptr, nullptr, hc, h1, red);     gbar(bar, target);
    mogP<false>(h1, qw + DH, qb + ND, nullptr, nullptr, xA, xB, red); gbar(bar, target);
    mogP<false>(xB, rw + DH, rb + ND, nullptr, nullptr, h1, h3, red); gbar(bar, target);
    gatesP(xB, h3, wih, whh, bih, bhh, cS, hn, red);            gbar(bar, target);
  }
}

// ================= fallback multi-launch kernels (proven) =================

template<bool EMB>
__global__ __launch_bounds__(256) void mog_phase(
    const float* __restrict__ actT, const float* __restrict__ W,
    const float* __restrict__ bias, const float* __restrict__ multT,
    const float* __restrict__ emb, const int* __restrict__ tok,
    float* __restrict__ outT)
{
  const int tid = threadIdx.x;
  const int wv = tid >> 6;
  const int lane = tid & 63;
  const int c0 = blockIdx.x * 4;
  __shared__ float red[4][4][64];

  float acc[4] = {0.f, 0.f, 0.f, 0.f};
  const int kb = wv * 256;
  const float* ap = actT + (size_t)kb * NB + lane;

  for (int k = 0; k < 256; k += 8) {
    float hv[8];
#pragma unroll
    for (int q = 0; q < 8; ++q) hv[q] = ap[(k + q) * NB];
#pragma unroll
    for (int c = 0; c < 4; ++c)
      acc[c] = dot8_f32(hv, W + (size_t)(c0 + c) * ND + kb + k, acc[c]);
  }
#pragma unroll
  for (int c = 0; c < 4; ++c) red[wv][c][lane] = acc[c];
  __syncthreads();

  const int c = tid >> 6, b = tid & 63;
  float z = red[0][c][b] + red[1][c][b] + red[2][c][b] + red[3][c][b];
  z += bias[c0 + c];
  float g = 2.f * sigf(z);
  float m;
  if (EMB) m = emb[(size_t)tok[b] * ND + (c0 + c)];
  else     m = multT[(size_t)(c0 + c) * NB + b];
  outT[(size_t)(c0 + c) * NB + b] = g * m;
}

__global__ __launch_bounds__(256) void lstm_gates2(
    const float* __restrict__ xT, const float* __restrict__ hT,
    const float* __restrict__ Wih, const float* __restrict__ Whh,
    const float* __restrict__ bih, const float* __restrict__ bhh,
    float* __restrict__ cT, float* __restrict__ hOut)
{
  const int tid = threadIdx.x;
  const int wv = tid >> 6, lane = tid & 63;
  const int j0 = blockIdx.x * 2;
  __shared__ float red[4][16][64];
  float acc[16];
#pragma unroll
  for (int i = 0; i < 16; ++i) acc[i] = 0.f;
  const int kb = wv * 256;
  const float* xp = xT + (size_t)kb * NB + lane;
  const float* hp = hT + (size_t)kb * NB + lane;

  for (int k = 0; k < 256; k += 8) {
    float xv[8], hv[8];
#pragma unroll
    for (int q = 0; q < 8; ++q) { xv[q] = xp[(k + q) * NB]; hv[q] = hp[(k + q) * NB]; }
#pragma unroll
    for (int jj = 0; jj < 2; ++jj)
#pragma unroll
      for (int g = 0; g < 4; ++g) {
        const size_t row = (size_t)(g * ND + j0 + jj) * ND + kb + k;
        acc[jj * 8 + g]     = dot8_f32(xv, Wih + row, acc[jj * 8 + g]);
        acc[jj * 8 + 4 + g] = dot8_f32(hv, Whh + row, acc[jj * 8 + 4 + g]);
      }
  }
#pragma unroll
  for (int i = 0; i < 16; ++i) red[wv][i][lane] = acc[i];
  __syncthreads();

  if (tid < 128) {
    const int b = tid & 63, jj = tid >> 6;
    const int j = j0 + jj;
    float pre[4];
#pragma unroll
    for (int g = 0; g < 4; ++g) {
      float s = 0.f;
#pragma unroll
      for (int w = 0; w < 4; ++w) s += red[w][jj * 8 + g][b] + red[w][jj * 8 + 4 + g][b];
      pre[g] = s + bih[g * ND + j] + bhh[g * ND + j];
    }
    float iv = sigf(pre[0]), fv = sigf(pre[1]);
    float gv = tanhf(pre[2]), ov = sigf(pre[3]);
    float cn = fv * cT[(size_t)j * NB + b] + iv * gv;
    float hn = ov * tanhf(cn);
    cT[(size_t)j * NB + b] = cn;
    hOut[(size_t)j * NB + b] = hn;
  }
}

__global__ __launch_bounds__(256) void decode_k(
    const float* __restrict__ hT, const float* __restrict__ W,
    const float* __restrict__ decb, float* __restrict__ out)
{
  const int tid = threadIdx.x;
  const int wv = tid >> 6, lane = tid & 63;
  const int v0 = blockIdx.x * 4;
  __shared__ float red[4][4][64];
  float acc[4] = {0.f, 0.f, 0.f, 0.f};
  const int kb = wv * 256;
  const float* hp = hT + (size_t)kb * NB + lane;

  for (int k = 0; k < 256; k += 8) {
    float hv[8];
#pragma unroll
    for (int q = 0; q < 8; ++q) hv[q] = hp[(k + q) * NB];
#pragma unroll
    for (int c = 0; c < 4; ++c)
      acc[c] = dot8_f32(hv, W + (size_t)(v0 + c) * ND + kb + k, acc[c]);
  }
#pragma unroll
  for (int c = 0; c < 4; ++c) red[wv][c][lane] = acc[c];
  __syncthreads();

  const int c = tid >> 6, b = tid & 63;
  float z = red[0][c][b] + red[1][c][b] + red[2][c][b] + red[3][c][b];
  z += decb[v0 + c];
  out[(size_t)b * NV + v0 + c] = z;
}

// ---- batched decode GEMM over the whole h-history ----
__global__ __launch_bounds__(256) void decode_gemm(
    const float* __restrict__ A,      // [t][k][b]
    const float* __restrict__ Bw,     // [n][k]
    const float* __restrict__ bias,
    float* __restrict__ C)            // [t][b][n]
{
  const int tid = threadIdx.x;
  const int bid = blockIdx.x;
  const int mt = bid & 255;
  const int nt = bid >> 8;
  const int n0 = nt * 64;

  __shared__ float As[2048];
  __shared__ float Bs[2048];

  const int tm = tid >> 4, tn = tid & 15;
  float acc[4][4] = {{0.f}};
  const float* Abase = A + (size_t)mt * (ND * NB);

  for (int k0 = 0; k0 < ND; k0 += 32) {
    __syncthreads();
    {
      const float4* src = (const float4*)(Abase + (size_t)k0 * NB);
      ((float4*)As)[tid] = src[tid];
      ((float4*)As)[tid + 256] = src[tid + 256];
    }
#pragma unroll
    for (int i = 0; i < 2; ++i) {
      int f = tid + i * 256;
      int n = f >> 3;
      int kc = f & 7;
      int gn = n0 + n;
      float4 v = make_float4(0.f, 0.f, 0.f, 0.f);
      if (gn < NV) v = *(const float4*)(Bw + (size_t)gn * ND + k0 + kc * 4);
      int k = kc * 4;
      int n4 = n >> 2, nr = n & 3;
      Bs[(k + 0) * 64 + ((n4 ^ ((k + 0) & 7)) << 2) + nr] = v.x;
      Bs[(k + 1) * 64 + ((n4 ^ ((k + 1) & 7)) << 2) + nr] = v.y;
      Bs[(k + 2) * 64 + ((n4 ^ ((k + 2) & 7)) << 2) + nr] = v.z;
      Bs[(k + 3) * 64 + ((n4 ^ ((k + 3) & 7)) << 2) + nr] = v.w;
    }
    __syncthreads();
#pragma unroll
    for (int kk = 0; kk < 32; ++kk) {
      float a4[4], b4[4];
      *(float4*)a4 = *(const float4*)(As + kk * 64 + tm * 4);
      *(float4*)b4 = *(const float4*)(Bs + kk * 64 + ((tn ^ (kk & 7)) << 2));
#pragma unroll
      for (int i = 0; i < 4; ++i)
#pragma unroll
        for (int j = 0; j < 4; ++j)
          acc[i][j] = fmaf(a4[i], b4[j], acc[i][j]);
    }
  }

  const int nb = n0 + tn * 4;
  float db[4];
#pragma unroll
  for (int j = 0; j < 4; ++j) db[j] = (nb + j < NV) ? bias[nb + j] : 0.f;
  float* Crow = C + (size_t)mt * ((size_t)NB * NV);
#pragma unroll
  for (int i = 0; i < 4; ++i) {
    const int b = tm * 4 + i;
    float* cp = Crow + (size_t)b * NV + nb;
    if (nb + 3 < NV) {
      float4 v;
      v.x = acc[i][0] + db[0]; v.y = acc[i][1] + db[1];
      v.z = acc[i][2] + db[2]; v.w = acc[i][3] + db[3];
      *(float4*)cp = v;
    } else {
#pragma unroll
      for (int j = 0; j < 4; ++j)
        if (nb + j < NV) cp[j] = acc[i][j] + db[j];
    }
  }
}

__global__ void finalize(const float* __restrict__ hT, const float* __restrict__ cT,
                         float* __restrict__ out) {
  int i = blockIdx.x * 256 + threadIdx.x;
  int k = i >> 6, b = i & 63;
  size_t base = (size_t)SEQ_LEN * NB * NV;
  out[base + (size_t)b * ND + k] = hT[i];
  out[base + (size_t)NB * ND + (size_t)b * ND + k] = cT[i];
}

extern "C" void kernel_launch(void* const* d_in, const int* in_sizes, int n_in,
                              void* d_out, int out_size, void* d_ws, size_t ws_size,
                              hipStream_t stream)
{
  float* out = (float*)d_out;
  const unsigned long long expect_out = (unsigned long long)SEQ_LEN * NB * NV + 2ull * NB * ND;

  auto flood = [&](float v) {
    unsigned long long n = (unsigned long long)out_size;
    unsigned int g = (unsigned int)((n + 255) / 256);
    floodk<<<g, 256, 0, stream>>>(out, v, n);
  };
  const int expect_sz[14] = {
    SEQ_LEN * NB, NV * ND, 2 * ND * ND, 2 * ND, 2 * ND * ND, 2 * ND,
    4 * ND * ND, 4 * ND * ND, 4 * ND, 4 * ND, NV * ND, NV, NB * ND, NB * ND };
  if (n_in != 14) { flood(1000.f); return; }
  for (int i = 0; i < 14; ++i)
    if (in_sizes[i] != expect_sz[i]) { flood(1100.f + 100.f * i); return; }
  if ((unsigned long long)out_size != expect_out) { flood(2500.f); return; }

  float* ws = (float*)d_ws;
  const size_t SB = (size_t)ND * NB;   // 65536
  if (ws_size < 7 * SB * sizeof(float)) { flood(2600.f); return; }

  const int*   tokens = (const int*)d_in[0];
  const float* emb  = (const float*)d_in[1];
  const float* qw   = (const float*)d_in[2];
  const float* qb   = (const float*)d_in[3];
  const float* rw   = (const float*)d_in[4];
  const float* rb   = (const float*)d_in[5];
  const float* wih  = (const float*)d_in[6];
  const float* whh  = (const float*)d_in[7];
  const float* bih  = (const float*)d_in[8];
  const float* bhh  = (const float*)d_in[9];
  const float* decw = (const float*)d_in[10];
  const float* decb = (const float*)d_in[11];
  const float* h0   = (const float*)d_in[12];
  const float* c0   = (const float*)d_in[13];

  float* xA = ws + 0 * SB;
  float* xB = ws + 1 * SB;
  float* h1 = ws + 2 * SB;
  float* h3 = ws + 3 * SB;
  float* cS = ws + 4 * SB;
  float* hHist = ws + 5 * SB;          // 257 slots
  u32* bar = (u32*)(ws + (5 + SEQ_LEN + 1) * SB);

  const size_t DH = (size_t)ND * ND;
  const bool big = ws_size >= ((5 + SEQ_LEN + 1) * SB + 64) * sizeof(float);

  if (big) {
    init_state<<<256, 256, 0, stream>>>(h0, c0, hHist, cS, bar);
    seq_kernel<<<NBLK, 512, 0, stream>>>(tokens, emb, qw, qb, rw, rb,
                                         wih, whh, bih, bhh,
                                         xA, xB, h1, h3, cS, hHist, bar);
    decode_gemm<<<157 * 256, 256, 0, stream>>>(hHist + SB, decw, decb, out);
    finalize<<<256, 256, 0, stream>>>(hHist + (size_t)SEQ_LEN * SB, cS, out);
  } else {
    float* hA = hHist;
    float* hB = hHist + SB;
    init_state<<<256, 256, 0, stream>>>(h0, c0, hA, cS, bar);
    float* hc = hA;
    float* hn = hB;
    for (int t = 0; t < SEQ_LEN; ++t) {
      const int* tk = tokens + (size_t)t * NB;
      mog_phase<true ><<<256, 256, 0, stream>>>(hc, qw, qb, nullptr, emb, tk, xA);
      mog_phase<false><<<256, 256, 0, stream>>>(xA, rw, rb, hc, nullptr, nullptr, h1);
      mog_phase<false><<<256, 256, 0, stream>>>(h1, qw + DH, qb + ND, xA, nullptr, nullptr, xB);
      mog_phase<false><<<256, 256, 0, stream>>>(xB, rw + DH, rb + ND, h1, nullptr, nullptr, h3);
      lstm_gates2<<<512, 256, 0, stream>>>(xB, h3, wih, whh, bih, bhh, cS, hn);
      decode_k<<<2500, 256, 0, stream>>>(hn, decw, decb, out + (size_t)t * NB * NV);
      float* tmp = hc; hc = hn; hn = tmp;
    }
    finalize<<<256, 256, 0, stream>>>(hc, cS, out);
  }
}

// Round 8
// 44811.050 us; speedup vs baseline: 1.6069x; 1.4726x over previous
//
#include <hip/hip_runtime.h>
#include <hip/hip_bf16.h>

#define SEQ_LEN 256
#define NB 64
#define NV 10000
#define ND 1024
#define NBLK 256

typedef unsigned int u32;
typedef unsigned short u16;

__device__ __forceinline__ float sigf(float z) { return 1.f / (1.f + expf(-z)); }

__device__ __forceinline__ float bflo(u32 u) {
  union { u32 i; float f; } v; v.i = u << 16; return v.f;
}
__device__ __forceinline__ float bfhi(u32 u) {
  union { u32 i; float f; } v; v.i = u & 0xffff0000u; return v.f;
}
__device__ __forceinline__ u16 f2bf(float f) {   // RNE
  u32 u = __float_as_uint(f);
  u32 r = u + 0x7FFFu + ((u >> 16) & 1u);
  return (u16)(r >> 16);
}

__device__ __forceinline__ float dot8_f32(const float* hv, const float* wp, float acc) {
  float4 w0 = *(const float4*)wp;
  float4 w1 = *(const float4*)(wp + 4);
  acc += hv[0] * w0.x; acc += hv[1] * w0.y; acc += hv[2] * w0.z; acc += hv[3] * w0.w;
  acc += hv[4] * w1.x; acc += hv[5] * w1.y; acc += hv[6] * w1.z; acc += hv[7] * w1.w;
  return acc;
}

// 8 bf16 weights from LDS (wave-uniform address -> broadcast, conflict-free)
__device__ __forceinline__ float dot8_w(const float* hv, const u16* wp, float acc) {
  uint4 wu = *(const uint4*)wp;
  acc = fmaf(hv[0], bflo(wu.x), acc); acc = fmaf(hv[1], bfhi(wu.x), acc);
  acc = fmaf(hv[2], bflo(wu.y), acc); acc = fmaf(hv[3], bfhi(wu.y), acc);
  acc = fmaf(hv[4], bflo(wu.z), acc); acc = fmaf(hv[5], bfhi(wu.z), acc);
  acc = fmaf(hv[6], bflo(wu.w), acc); acc = fmaf(hv[7], bfhi(wu.w), acc);
  return acc;
}

// ---- diagnostic flood (f32 out) ----
__global__ void floodk(float* out, float val, unsigned long long n) {
  unsigned long long i = (unsigned long long)blockIdx.x * 256 + threadIdx.x;
  if (i < n) out[i] = val;
}

// ---- init: transpose states to feature-major, zero barrier lines ----
__global__ void init_state(const float* __restrict__ h0, const float* __restrict__ c0,
                           float* __restrict__ hT, float* __restrict__ cT, u32* bar) {
  int i = blockIdx.x * 256 + threadIdx.x;   // 0..65535
  int k = i >> 6, b = i & 63;
  hT[i] = h0[b * ND + k];
  cT[i] = c0[b * ND + k];
  if (i < 64) bar[i] = 0u;                  // count @ bar[0], gen @ bar[32]
}

// ================= persistent fused sequence kernel =================
// grid 256 blocks x 512 thr (8 waves), 1 block/CU. Weights bf16 in LDS.

__device__ __forceinline__ void gbar(u32* bar, u32& target) {
  __syncthreads();
  if (threadIdx.x == 0) {
    u32* cnt = bar;
    u32* gen = bar + 32;                    // separate cacheline
    target += NBLK;
    __threadfence();
    u32 old = __hip_atomic_fetch_add(cnt, 1u, __ATOMIC_ACQ_REL, __HIP_MEMORY_SCOPE_AGENT);
    if (old == target - 1) {
      __hip_atomic_store(gen, target, __ATOMIC_RELEASE, __HIP_MEMORY_SCOPE_AGENT);
    } else {
      while (__hip_atomic_load(gen, __ATOMIC_ACQUIRE, __HIP_MEMORY_SCOPE_AGENT) < target) {
        __builtin_amdgcn_s_sleep(4);
      }
    }
    __threadfence();
  }
  __syncthreads();
}

// mog phase: out[c][b] = 2*sig(sum_k act[k][b]*W[c][k] + bias[c]) * mult
// Wl = LDS slice [4 cols][1024 k] bf16.
template<bool EMB>
__device__ __forceinline__ void mogP(
    const float* __restrict__ actT, const u16* Wl,
    const float* __restrict__ bias, const float* __restrict__ emb,
    const int* __restrict__ tok, const float* __restrict__ multT,
    float* __restrict__ outT, float* red)
{
  const int tid = threadIdx.x;
  const int wv = tid >> 6, lane = tid & 63;
  const int c0 = blockIdx.x * 4;
  const int kb = wv * 128;
  float acc[4] = {0.f, 0.f, 0.f, 0.f};
  const float* ap = actT + (size_t)kb * NB + lane;

  for (int k = 0; k < 128; k += 8) {
    float hv[8];
#pragma unroll
    for (int q = 0; q < 8; ++q) hv[q] = ap[(k + q) * NB];
#pragma unroll
    for (int c = 0; c < 4; ++c)
      acc[c] = dot8_w(hv, Wl + c * 1024 + kb + k, acc[c]);
  }
#pragma unroll
  for (int c = 0; c < 4; ++c) red[(wv * 16 + c) * 64 + lane] = acc[c];
  __syncthreads();

  if (tid < 256) {
    const int c = tid >> 6, b = tid & 63;
    float z = 0.f;
#pragma unroll
    for (int w = 0; w < 8; ++w) z += red[(w * 16 + c) * 64 + b];
    z += bias[c0 + c];
    float g = 2.f * sigf(z);
    float m = EMB ? emb[(size_t)tok[b] * ND + (c0 + c)]
                  : multT[(size_t)(c0 + c) * NB + b];
    outT[(size_t)(c0 + c) * NB + b] = g * m;
  }
}

// gates phase: block owns 4 hidden cols (16 gate rows, local row r = jj*4+g);
// waves 0-3 x-half, 4-7 h-half; weights bf16 LDS.
__device__ __forceinline__ void gatesP(
    const float* __restrict__ xT, const float* __restrict__ hT,
    const u16* wG,
    const float* __restrict__ bih, const float* __restrict__ bhh,
    float* __restrict__ cT, float* __restrict__ hOut, float* red)
{
  const int tid = threadIdx.x;
  const int wv = tid >> 6, lane = tid & 63;
  const int j0 = blockIdx.x * 4;
  const int half = wv >> 2, kq = wv & 3;
  const int kb = kq * 256;
  const float* ap = (half ? hT : xT) + (size_t)kb * NB + lane;
  const u16* Wb = wG + half * (16 * 1024);

  float acc[16];
#pragma unroll
  for (int i = 0; i < 16; ++i) acc[i] = 0.f;

  for (int k = 0; k < 256; k += 8) {
    float av[8];
#pragma unroll
    for (int q = 0; q < 8; ++q) av[q] = ap[(k + q) * NB];
#pragma unroll
    for (int r = 0; r < 16; ++r)
      acc[r] = dot8_w(av, Wb + r * 1024 + kb + k, acc[r]);
  }
#pragma unroll
  for (int i = 0; i < 16; ++i) red[(wv * 16 + i) * 64 + lane] = acc[i];
  __syncthreads();

  if (tid < 256) {
    const int jj = tid >> 6, b = tid & 63;
    const int j = j0 + jj;
    float pre[4];
#pragma unroll
    for (int g = 0; g < 4; ++g) {
      float s = 0.f;
#pragma unroll
      for (int w = 0; w < 8; ++w) s += red[(w * 16 + jj * 4 + g) * 64 + b];
      pre[g] = s + bih[g * ND + j] + bhh[g * ND + j];
    }
    float iv = sigf(pre[0]), fv = sigf(pre[1]);
    float gv = tanhf(pre[2]), ov = sigf(pre[3]);
    float cn = fv * cT[(size_t)j * NB + b] + iv * gv;
    float hn = ov * tanhf(cn);
    cT[(size_t)j * NB + b] = cn;
    hOut[(size_t)j * NB + b] = hn;
  }
}

__global__ __launch_bounds__(512) void seq_kernel(
    const int* __restrict__ tokens, const float* __restrict__ emb,
    const float* __restrict__ qw, const float* __restrict__ qb,
    const float* __restrict__ rw, const float* __restrict__ rb,
    const float* __restrict__ wih, const float* __restrict__ whh,
    const float* __restrict__ bih, const float* __restrict__ bhh,
    float* __restrict__ xA, float* __restrict__ xB,
    float* __restrict__ h1, float* __restrict__ h3,
    float* __restrict__ cS, float* __restrict__ hHist, u32* bar)
{
  __shared__ u16 wMog[4 * 4 * 1024];     // 32 KB: [mat][col][k]
  __shared__ u16 wG[2 * 16 * 1024];      // 64 KB: [mat][row r=jj*4+g][k]
  __shared__ float red[8 * 16 * 64];     // 32 KB

  const int tid = threadIdx.x;
  const int c0 = blockIdx.x * 4;
  const size_t DH = (size_t)ND * ND;
  const size_t SB = (size_t)ND * NB;

  // ---- one-time LDS weight fill (f32 -> bf16 RNE) ----
  {
    const float* msrc[4] = {qw, rw, qw + DH, rw + DH};
#pragma unroll
    for (int m = 0; m < 4; ++m)
      for (int c = 0; c < 4; ++c) {
        const float* src = msrc[m] + (size_t)(c0 + c) * ND;
        u16* dst = wMog + (m * 4 + c) * 1024;
        for (int k = tid; k < ND; k += 512) dst[k] = f2bf(src[k]);
      }
#pragma unroll
    for (int m = 0; m < 2; ++m) {
      const float* W = m ? whh : wih;
      for (int r = 0; r < 16; ++r) {
        const float* src = W + ((size_t)(r & 3) * ND + c0 + (r >> 2)) * ND;
        u16* dst = wG + (m * 16 + r) * 1024;
        for (int k = tid; k < ND; k += 512) dst[k] = f2bf(src[k]);
      }
    }
  }
  __syncthreads();

  u32 target = 0;
  for (int t = 0; t < SEQ_LEN; ++t) {
    const int* tok = tokens + (size_t)t * NB;
    float* hc = hHist + (size_t)t * SB;
    float* hn = hc + SB;
    mogP<true >(hc, wMog + 0 * 4096, qb,      emb, tok, nullptr, xA, red);  gbar(bar, target);
    mogP<false>(xA, wMog + 1 * 4096, rb,      nullptr, nullptr, hc, h1, red); gbar(bar, target);
    mogP<false>(h1, wMog + 2 * 4096, qb + ND, nullptr, nullptr, xA, xB, red); gbar(bar, target);
    mogP<false>(xB, wMog + 3 * 4096, rb + ND, nullptr, nullptr, h1, h3, red); gbar(bar, target);
    gatesP(xB, h3, wG, bih, bhh, cS, hn, red);                               gbar(bar, target);
  }
}

// ================= fallback multi-launch kernels (proven) =================

template<bool EMB>
__global__ __launch_bounds__(256) void mog_phase(
    const float* __restrict__ actT, const float* __restrict__ W,
    const float* __restrict__ bias, const float* __restrict__ multT,
    const float* __restrict__ emb, const int* __restrict__ tok,
    float* __restrict__ outT)
{
  const int tid = threadIdx.x;
  const int wv = tid >> 6;
  const int lane = tid & 63;
  const int c0 = blockIdx.x * 4;
  __shared__ float red[4][4][64];

  float acc[4] = {0.f, 0.f, 0.f, 0.f};
  const int kb = wv * 256;
  const float* ap = actT + (size_t)kb * NB + lane;

  for (int k = 0; k < 256; k += 8) {
    float hv[8];
#pragma unroll
    for (int q = 0; q < 8; ++q) hv[q] = ap[(k + q) * NB];
#pragma unroll
    for (int c = 0; c < 4; ++c)
      acc[c] = dot8_f32(hv, W + (size_t)(c0 + c) * ND + kb + k, acc[c]);
  }
#pragma unroll
  for (int c = 0; c < 4; ++c) red[wv][c][lane] = acc[c];
  __syncthreads();

  const int c = tid >> 6, b = tid & 63;
  float z = red[0][c][b] + red[1][c][b] + red[2][c][b] + red[3][c][b];
  z += bias[c0 + c];
  float g = 2.f * sigf(z);
  float m;
  if (EMB) m = emb[(size_t)tok[b] * ND + (c0 + c)];
  else     m = multT[(size_t)(c0 + c) * NB + b];
  outT[(size_t)(c0 + c) * NB + b] = g * m;
}

__global__ __launch_bounds__(256) void lstm_gates2(
    const float* __restrict__ xT, const float* __restrict__ hT,
    const float* __restrict__ Wih, const float* __restrict__ Whh,
    const float* __restrict__ bih, const float* __restrict__ bhh,
    float* __restrict__ cT, float* __restrict__ hOut)
{
  const int tid = threadIdx.x;
  const int wv = tid >> 6, lane = tid & 63;
  const int j0 = blockIdx.x * 2;
  __shared__ float red[4][16][64];
  float acc[16];
#pragma unroll
  for (int i = 0; i < 16; ++i) acc[i] = 0.f;
  const int kb = wv * 256;
  const float* xp = xT + (size_t)kb * NB + lane;
  const float* hp = hT + (size_t)kb * NB + lane;

  for (int k = 0; k < 256; k += 8) {
    float xv[8], hv[8];
#pragma unroll
    for (int q = 0; q < 8; ++q) { xv[q] = xp[(k + q) * NB]; hv[q] = hp[(k + q) * NB]; }
#pragma unroll
    for (int jj = 0; jj < 2; ++jj)
#pragma unroll
      for (int g = 0; g < 4; ++g) {
        const size_t row = (size_t)(g * ND + j0 + jj) * ND + kb + k;
        acc[jj * 8 + g]     = dot8_f32(xv, Wih + row, acc[jj * 8 + g]);
        acc[jj * 8 + 4 + g] = dot8_f32(hv, Whh + row, acc[jj * 8 + 4 + g]);
      }
  }
#pragma unroll
  for (int i = 0; i < 16; ++i) red[wv][i][lane] = acc[i];
  __syncthreads();

  if (tid < 128) {
    const int b = tid & 63, jj = tid >> 6;
    const int j = j0 + jj;
    float pre[4];
#pragma unroll
    for (int g = 0; g < 4; ++g) {
      float s = 0.f;
#pragma unroll
      for (int w = 0; w < 4; ++w) s += red[w][jj * 8 + g][b] + red[w][jj * 8 + 4 + g][b];
      pre[g] = s + bih[g * ND + j] + bhh[g * ND + j];
    }
    float iv = sigf(pre[0]), fv = sigf(pre[1]);
    float gv = tanhf(pre[2]), ov = sigf(pre[3]);
    float cn = fv * cT[(size_t)j * NB + b] + iv * gv;
    float hn = ov * tanhf(cn);
    cT[(size_t)j * NB + b] = cn;
    hOut[(size_t)j * NB + b] = hn;
  }
}

__global__ __launch_bounds__(256) void decode_k(
    const float* __restrict__ hT, const float* __restrict__ W,
    const float* __restrict__ decb, float* __restrict__ out)
{
  const int tid = threadIdx.x;
  const int wv = tid >> 6, lane = tid & 63;
  const int v0 = blockIdx.x * 4;
  __shared__ float red[4][4][64];
  float acc[4] = {0.f, 0.f, 0.f, 0.f};
  const int kb = wv * 256;
  const float* hp = hT + (size_t)kb * NB + lane;

  for (int k = 0; k < 256; k += 8) {
    float hv[8];
#pragma unroll
    for (int q = 0; q < 8; ++q) hv[q] = hp[(k + q) * NB];
#pragma unroll
    for (int c = 0; c < 4; ++c)
      acc[c] = dot8_f32(hv, W + (size_t)(v0 + c) * ND + kb + k, acc[c]);
  }
#pragma unroll
  for (int c = 0; c < 4; ++c) red[wv][c][lane] = acc[c];
  __syncthreads();

  const int c = tid >> 6, b = tid & 63;
  float z = red[0][c][b] + red[1][c][b] + red[2][c][b] + red[3][c][b];
  z += decb[v0 + c];
  out[(size_t)b * NV + v0 + c] = z;
}

// ---- batched decode GEMM over the whole h-history ----
__global__ __launch_bounds__(256) void decode_gemm(
    const float* __restrict__ A,      // [t][k][b]
    const float* __restrict__ Bw,     // [n][k]
    const float* __restrict__ bias,
    float* __restrict__ C)            // [t][b][n]
{
  const int tid = threadIdx.x;
  const int bid = blockIdx.x;
  const int mt = bid & 255;
  const int nt = bid >> 8;
  const int n0 = nt * 64;

  __shared__ float As[2048];
  __shared__ float Bs[2048];

  const int tm = tid >> 4, tn = tid & 15;
  float acc[4][4] = {{0.f}};
  const float* Abase = A + (size_t)mt * (ND * NB);

  for (int k0 = 0; k0 < ND; k0 += 32) {
    __syncthreads();
    {
      const float4* src = (const float4*)(Abase + (size_t)k0 * NB);
      ((float4*)As)[tid] = src[tid];
      ((float4*)As)[tid + 256] = src[tid + 256];
    }
#pragma unroll
    for (int i = 0; i < 2; ++i) {
      int f = tid + i * 256;
      int n = f >> 3;
      int kc = f & 7;
      int gn = n0 + n;
      float4 v = make_float4(0.f, 0.f, 0.f, 0.f);
      if (gn < NV) v = *(const float4*)(Bw + (size_t)gn * ND + k0 + kc * 4);
      int k = kc * 4;
      int n4 = n >> 2, nr = n & 3;
      Bs[(k + 0) * 64 + ((n4 ^ ((k + 0) & 7)) << 2) + nr] = v.x;
      Bs[(k + 1) * 64 + ((n4 ^ ((k + 1) & 7)) << 2) + nr] = v.y;
      Bs[(k + 2) * 64 + ((n4 ^ ((k + 2) & 7)) << 2) + nr] = v.z;
      Bs[(k + 3) * 64 + ((n4 ^ ((k + 3) & 7)) << 2) + nr] = v.w;
    }
    __syncthreads();
#pragma unroll
    for (int kk = 0; kk < 32; ++kk) {
      float a4[4], b4[4];
      *(float4*)a4 = *(const float4*)(As + kk * 64 + tm * 4);
      *(float4*)b4 = *(const float4*)(Bs + kk * 64 + ((tn ^ (kk & 7)) << 2));
#pragma unroll
      for (int i = 0; i < 4; ++i)
#pragma unroll
        for (int j = 0; j < 4; ++j)
          acc[i][j] = fmaf(a4[i], b4[j], acc[i][j]);
    }
  }

  const int nb = n0 + tn * 4;
  float db[4];
#pragma unroll
  for (int j = 0; j < 4; ++j) db[j] = (nb + j < NV) ? bias[nb + j] : 0.f;
  float* Crow = C + (size_t)mt * ((size_t)NB * NV);
#pragma unroll
  for (int i = 0; i < 4; ++i) {
    const int b = tm * 4 + i;
    float* cp = Crow + (size_t)b * NV + nb;
    if (nb + 3 < NV) {
      float4 v;
      v.x = acc[i][0] + db[0]; v.y = acc[i][1] + db[1];
      v.z = acc[i][2] + db[2]; v.w = acc[i][3] + db[3];
      *(float4*)cp = v;
    } else {
#pragma unroll
      for (int j = 0; j < 4; ++j)
        if (nb + j < NV) cp[j] = acc[i][j] + db[j];
    }
  }
}

__global__ void finalize(const float* __restrict__ hT, const float* __restrict__ cT,
                         float* __restrict__ out) {
  int i = blockIdx.x * 256 + threadIdx.x;
  int k = i >> 6, b = i & 63;
  size_t base = (size_t)SEQ_LEN * NB * NV;
  out[base + (size_t)b * ND + k] = hT[i];
  out[base + (size_t)NB * ND + (size_t)b * ND + k] = cT[i];
}

extern "C" void kernel_launch(void* const* d_in, const int* in_sizes, int n_in,
                              void* d_out, int out_size, void* d_ws, size_t ws_size,
                              hipStream_t stream)
{
  float* out = (float*)d_out;
  const unsigned long long expect_out = (unsigned long long)SEQ_LEN * NB * NV + 2ull * NB * ND;

  auto flood = [&](float v) {
    unsigned long long n = (unsigned long long)out_size;
    unsigned int g = (unsigned int)((n + 255) / 256);
    floodk<<<g, 256, 0, stream>>>(out, v, n);
  };
  const int expect_sz[14] = {
    SEQ_LEN * NB, NV * ND, 2 * ND * ND, 2 * ND, 2 * ND * ND, 2 * ND,
    4 * ND * ND, 4 * ND * ND, 4 * ND, 4 * ND, NV * ND, NV, NB * ND, NB * ND };
  if (n_in != 14) { flood(1000.f); return; }
  for (int i = 0; i < 14; ++i)
    if (in_sizes[i] != expect_sz[i]) { flood(1100.f + 100.f * i); return; }
  if ((unsigned long long)out_size != expect_out) { flood(2500.f); return; }

  float* ws = (float*)d_ws;
  const size_t SB = (size_t)ND * NB;   // 65536
  if (ws_size < 7 * SB * sizeof(float)) { flood(2600.f); return; }

  const int*   tokens = (const int*)d_in[0];
  const float* emb  = (const float*)d_in[1];
  const float* qw   = (const float*)d_in[2];
  const float* qb   = (const float*)d_in[3];
  const float* rw   = (const float*)d_in[4];
  const float* rb   = (const float*)d_in[5];
  const float* wih  = (const float*)d_in[6];
  const float* whh  = (const float*)d_in[7];
  const float* bih  = (const float*)d_in[8];
  const float* bhh  = (const float*)d_in[9];
  const float* decw = (const float*)d_in[10];
  const float* decb = (const float*)d_in[11];
  const float* h0   = (const float*)d_in[12];
  const float* c0   = (const float*)d_in[13];

  float* xA = ws + 0 * SB;
  float* xB = ws + 1 * SB;
  float* h1 = ws + 2 * SB;
  float* h3 = ws + 3 * SB;
  float* cS = ws + 4 * SB;
  float* hHist = ws + 5 * SB;          // 257 slots
  u32* bar = (u32*)(ws + (5 + SEQ_LEN + 1) * SB);

  const size_t DH = (size_t)ND * ND;
  const bool big = ws_size >= ((5 + SEQ_LEN + 1) * SB + 64) * sizeof(float);

  if (big) {
    init_state<<<256, 256, 0, stream>>>(h0, c0, hHist, cS, bar);
    seq_kernel<<<NBLK, 512, 0, stream>>>(tokens, emb, qw, qb, rw, rb,
                                         wih, whh, bih, bhh,
                                         xA, xB, h1, h3, cS, hHist, bar);
    decode_gemm<<<157 * 256, 256, 0, stream>>>(hHist + SB, decw, decb, out);
    finalize<<<256, 256, 0, stream>>>(hHist + (size_t)SEQ_LEN * SB, cS, out);
  } else {
    float* hA = hHist;
    float* hB = hHist + SB;
    init_state<<<256, 256, 0, stream>>>(h0, c0, hA, cS, bar);
    float* hc = hA;
    float* hn = hB;
    for (int t = 0; t < SEQ_LEN; ++t) {
      const int* tk = tokens + (size_t)t * NB;
      mog_phase<true ><<<256, 256, 0, stream>>>(hc, qw, qb, nullptr, emb, tk, xA);
      mog_phase<false><<<256, 256, 0, stream>>>(xA, rw, rb, hc, nullptr, nullptr, h1);
      mog_phase<false><<<256, 256, 0, stream>>>(h1, qw + DH, qb + ND, xA, nullptr, nullptr, xB);
      mog_phase<false><<<256, 256, 0, stream>>>(xB, rw + DH, rb + ND, h1, nullptr, nullptr, h3);
      lstm_gates2<<<512, 256, 0, stream>>>(xB, h3, wih, whh, bih, bhh, cS, hn);
      decode_k<<<2500, 256, 0, stream>>>(hn, decw, decb, out + (size_t)t * NB * NV);
      float* tmp = hc; hc = hn; hn = tmp;
    }
    finalize<<<256, 256, 0, stream>>>(hc, cS, out);
  }
}